// Round 4
// baseline (339.058 us; speedup 1.0000x reference)
//
#include <hip/hip_runtime.h>
#include <math.h>

// LiquidEchoHead, two-kernel split with EXPLICIT 2-deep software pipelining.
//
// Diagnosis history: all prior structures (block-per-row fused, wave-per-row
// fused, naive split) sit at 2.3-3.8 TB/s delivered while the harness's own
// write-only fill kernel hits 6.9 TB/s. Back-computed in-flight bytes/CU was
// ~2.3 KB vs ~9 KB needed: waves drain loads, then spend 1000+ cycles in
// serial sincos + shuffle-butterfly windows with ZERO memory ops outstanding
// (convoy effect). Fix: ping-pong register staging so every compute window
// has the next work item's loads in flight.
//
//   K1 (alpha_kernel_fast): wave owns 4 rows, A/B row pipeline:
//       load r0->A; load r1->B; comp A; load r2->A; comp B; load r3->B;
//       comp A; comp B.   (16 KB in flight under every compute window)
//   K2 (evolve_kernel_fast): flat grid-stride, 8 iters/thread, ping-pong
//       stage struct (6 float4 streams + alpha/t prefetched one iter ahead).
//
// Identity: cos(a)cos(b)-sin(a)sin(b)=cos(a+b); cos(a)sin(b)+sin(a)cos(b)=sin(a+b)
// -> evolution needs one sincos on (theta_r + theta_i).

#define PHI_F 1.61803398874989f

// ======================= K1 helpers (d4 == 512 fast path) ==================

__device__ __forceinline__ void k1_load_row(
    const float4* __restrict__ xr4, const float4* __restrict__ xi4,
    int lane, float4* xr, float4* xi)   // xr[8], xi[8] -> registers
{
    #pragma unroll
    for (int s = 0; s < 8; ++s) {
        int c = (s << 6) + lane;
        xr[s] = xr4[c];
        xi[s] = xi4[c];
    }
}

__device__ __forceinline__ float k1_compute_row(
    const float4* __restrict__ wq4, const float4* __restrict__ bq4,
    int lane, const float4* xr, const float4* xi, float inv_scale)
{
    float aR0 = 0.f, aI0 = 0.f, aR1 = 0.f, aI1 = 0.f;
    #pragma unroll
    for (int s = 0; s < 8; ++s) {
        int c = (s << 6) + lane;
        float4 wq = wq4[c];               // L1-resident after first row
        float4 bq = bq4[c];
        #pragma unroll
        for (int j = 0; j < 4; ++j) {
            float xrv = (&xr[s].x)[j];
            float xiv = (&xi[s].x)[j];
            float wl  = 1.f + fabsf((&wq.x)[j]);
            float th  = xrv * __builtin_amdgcn_rcpf(wl) + (&bq.x)[j];
            float sq, cq;
            __sincosf(th, &sq, &cq);
            // interf_real += cq*xr + sq*xi ; interf_imag += cq*xi - sq*xr
            if (s & 1) { aR1 = fmaf(cq, xrv, fmaf(sq, xiv, aR1));
                         aI1 = fmaf(cq, xiv, fmaf(-sq, xrv, aI1)); }
            else       { aR0 = fmaf(cq, xrv, fmaf(sq, xiv, aR0));
                         aI0 = fmaf(cq, xiv, fmaf(-sq, xrv, aI0)); }
        }
    }
    float accR = aR0 + aR1;
    float accI = aI0 + aI1;
    // Butterfly: all 64 lanes end with the row totals.
    #pragma unroll
    for (int off = 32; off > 0; off >>= 1) {
        accR += __shfl_xor(accR, off);
        accI += __shfl_xor(accI, off);
    }
    float interf = sqrtf(fmaf(accR, accR, accI * accI));
    float z   = fmaf(interf, inv_scale, -2.0f);
    float sig = 1.f / (1.f + __expf(-z));     // sigmoid(z)
    return __expf(sig - 1.f);                 // exp(-k*(1-sig)), k=1
}

// 4 rows per wave, ping-pong pipelined. Requires d4==512 and B%16==0.
__global__ __launch_bounds__(256) void alpha_kernel_fast(
    const float* __restrict__ x_real, const float* __restrict__ x_imag,
    const float* __restrict__ w_query, const float* __restrict__ b_query,
    float* __restrict__ alpha_out, float inv_scale)
{
    const int wave = (int)threadIdx.x >> 6;
    const int lane = (int)threadIdx.x & 63;
    const int row0 = (((int)blockIdx.x << 2) + wave) << 2;   // 4 rows/wave

    const float4* wq4 = (const float4*)w_query;
    const float4* bq4 = (const float4*)b_query;
    const float4* xr4 = (const float4*)x_real + ((size_t)row0 << 9);
    const float4* xi4 = (const float4*)x_imag + ((size_t)row0 << 9);

    float4 AR[8], AI[8], BR[8], BI[8];

    k1_load_row(xr4,        xi4,        lane, AR, AI);           // row0
    k1_load_row(xr4 + 512,  xi4 + 512,  lane, BR, BI);           // row0+1
    float a0 = k1_compute_row(wq4, bq4, lane, AR, AI, inv_scale); // waits A only
    if (lane == 0) alpha_out[row0 + 0] = a0;
    k1_load_row(xr4 + 1024, xi4 + 1024, lane, AR, AI);           // row0+2
    float a1 = k1_compute_row(wq4, bq4, lane, BR, BI, inv_scale);
    if (lane == 0) alpha_out[row0 + 1] = a1;
    k1_load_row(xr4 + 1536, xi4 + 1536, lane, BR, BI);           // row0+3
    float a2 = k1_compute_row(wq4, bq4, lane, AR, AI, inv_scale);
    if (lane == 0) alpha_out[row0 + 2] = a2;
    float a3 = k1_compute_row(wq4, bq4, lane, BR, BI, inv_scale);
    if (lane == 0) alpha_out[row0 + 3] = a3;
}

// Generic K1 fallback (any d4, any B): wave-per-row, unpipelined.
__global__ __launch_bounds__(256) void alpha_kernel_gen(
    const float* __restrict__ x_real, const float* __restrict__ x_imag,
    const float* __restrict__ w_query, const float* __restrict__ b_query,
    float* __restrict__ alpha_out, int d4, int B, float inv_scale)
{
    const int wave = (int)threadIdx.x >> 6;
    const int lane = (int)threadIdx.x & 63;
    const int row  = ((int)blockIdx.x << 2) + wave;
    if (row >= B) return;

    const size_t base4 = (size_t)row * d4;
    const float4* xr4 = (const float4*)x_real + base4;
    const float4* xi4 = (const float4*)x_imag + base4;
    const float4* wq4 = (const float4*)w_query;
    const float4* bq4 = (const float4*)b_query;

    float aR = 0.f, aI = 0.f;
    for (int c = lane; c < d4; c += 64) {
        float4 xr = xr4[c];
        float4 xi = xi4[c];
        float4 wq = wq4[c];
        float4 bq = bq4[c];
        #pragma unroll
        for (int j = 0; j < 4; ++j) {
            float xrv = (&xr.x)[j];
            float xiv = (&xi.x)[j];
            float wl  = 1.f + fabsf((&wq.x)[j]);
            float th  = xrv * __builtin_amdgcn_rcpf(wl) + (&bq.x)[j];
            float sq, cq;
            __sincosf(th, &sq, &cq);
            aR = fmaf(cq, xrv, fmaf(sq, xiv, aR));
            aI = fmaf(cq, xiv, fmaf(-sq, xrv, aI));
        }
    }
    #pragma unroll
    for (int off = 32; off > 0; off >>= 1) {
        aR += __shfl_xor(aR, off);
        aI += __shfl_xor(aI, off);
    }
    if (lane == 0) {
        float interf = sqrtf(fmaf(aR, aR, aI * aI));
        float z   = fmaf(interf, inv_scale, -2.0f);
        float sig = 1.f / (1.f + __expf(-z));
        alpha_out[row] = __expf(sig - 1.f);
    }
}

// ======================= K2 (d4 == 512 fast path) ==========================

struct K2Stage {
    float4 xr, xi, mr, mi, wo, bo;
    float  al, tp;
};

__device__ __forceinline__ K2Stage k2_load(
    int idx,
    const float4* __restrict__ xr4, const float4* __restrict__ xi4,
    const float4* __restrict__ mr4, const float4* __restrict__ mi4,
    const float4* __restrict__ wo4, const float4* __restrict__ bo4,
    const float* __restrict__ alpha_in, const float* __restrict__ t_arr)
{
    K2Stage s;
    const int row = idx >> 9;       // d4 == 512
    const int col = idx & 511;
    s.xr = xr4[idx];
    s.xi = xi4[idx];
    s.mr = mr4[idx];
    s.mi = mi4[idx];
    s.wo = wo4[col];                // L2-hot broadcast
    s.bo = bo4[col];
    s.al = alpha_in[row];           // wave-uniform (row spans 512 float4s)
    s.tp = t_arr[row];
    return s;
}

__device__ __forceinline__ void k2_compute(
    int idx, const K2Stage& s,
    float4* __restrict__ or4, float4* __restrict__ oi4)
{
    const float alpha = s.al;
    const float beta  = 1.f - alpha;
    const float tphi2 = 2.0f * PHI_F * s.tp;
    float4 oR, oI;
    #pragma unroll
    for (int j = 0; j < 4; ++j) {
        float br = fmaf(alpha, (&s.xr.x)[j], beta * (&s.mr.x)[j]);
        float bi = fmaf(alpha, (&s.xi.x)[j], beta * (&s.mi.x)[j]);
        float wl = 1.f + fabsf((&s.wo.x)[j]);
        float ang = fmaf(br + bi, __builtin_amdgcn_rcpf(wl),
                         fmaf(2.f, (&s.bo.x)[j], tphi2));
        float sv, cv;
        __sincosf(ang, &sv, &cv);
        (&oR.x)[j] = cv;   // evolved_real = cos(theta_r + theta_i)
        (&oI.x)[j] = sv;   // evolved_imag = sin(theta_r + theta_i)
    }
    or4[idx] = oR;
    oi4[idx] = oI;
}

// Flat grid-stride, ping-pong 2-deep pipeline. Requires d4==512.
__global__ __launch_bounds__(256) void evolve_kernel_fast(
    const float* __restrict__ x_real, const float* __restrict__ x_imag,
    const float* __restrict__ t_arr,
    const float* __restrict__ w_osc, const float* __restrict__ b_osc,
    const float* __restrict__ mem_r, const float* __restrict__ mem_i,
    const float* __restrict__ alpha_in,
    float* __restrict__ out_r, float* __restrict__ out_i, int n4)
{
    const float4* xr4 = (const float4*)x_real;
    const float4* xi4 = (const float4*)x_imag;
    const float4* mr4 = (const float4*)mem_r;
    const float4* mi4 = (const float4*)mem_i;
    const float4* wo4 = (const float4*)w_osc;
    const float4* bo4 = (const float4*)b_osc;
    float4* or4 = (float4*)out_r;
    float4* oi4 = (float4*)out_i;

    const int stride = (int)gridDim.x << 8;
    int i = ((int)blockIdx.x << 8) + (int)threadIdx.x;
    if (i >= n4) return;

    K2Stage A = k2_load(i, xr4, xi4, mr4, mi4, wo4, bo4, alpha_in, t_arr);
    int j = i + stride;
    while (j < n4) {
        K2Stage Bs = k2_load(j, xr4, xi4, mr4, mi4, wo4, bo4, alpha_in, t_arr);
        k2_compute(i, A, or4, oi4);          // B's loads stay in flight
        i = j + stride;
        if (i >= n4) { k2_compute(j, Bs, or4, oi4); return; }
        A = k2_load(i, xr4, xi4, mr4, mi4, wo4, bo4, alpha_in, t_arr);
        k2_compute(j, Bs, or4, oi4);         // A's loads stay in flight
        j = i + stride;
    }
    k2_compute(i, A, or4, oi4);
}

// Generic K2 fallback: block-per-row, unpipelined.
__global__ __launch_bounds__(256) void evolve_kernel_gen(
    const float* __restrict__ x_real, const float* __restrict__ x_imag,
    const float* __restrict__ t_arr,
    const float* __restrict__ w_osc, const float* __restrict__ b_osc,
    const float* __restrict__ mem_r, const float* __restrict__ mem_i,
    const float* __restrict__ alpha_in,
    float* __restrict__ out_r, float* __restrict__ out_i, int d4)
{
    const int row = blockIdx.x;
    const float alpha = alpha_in[row];
    const float beta  = 1.f - alpha;
    const float tphi2 = 2.0f * PHI_F * t_arr[row];

    const size_t base4 = (size_t)row * d4;
    const float4* xr4 = (const float4*)x_real + base4;
    const float4* xi4 = (const float4*)x_imag + base4;
    const float4* mr4 = (const float4*)mem_r + base4;
    const float4* mi4 = (const float4*)mem_i + base4;
    const float4* wo4 = (const float4*)w_osc;
    const float4* bo4 = (const float4*)b_osc;
    float4* or4 = (float4*)out_r + base4;
    float4* oi4 = (float4*)out_i + base4;

    for (int c = (int)threadIdx.x; c < d4; c += 256) {
        float4 xr = xr4[c];
        float4 xi = xi4[c];
        float4 mr = mr4[c];
        float4 mi = mi4[c];
        float4 wo = wo4[c];
        float4 bo = bo4[c];
        float4 oR, oI;
        #pragma unroll
        for (int j = 0; j < 4; ++j) {
            float br = fmaf(alpha, (&xr.x)[j], beta * (&mr.x)[j]);
            float bi = fmaf(alpha, (&xi.x)[j], beta * (&mi.x)[j]);
            float wl = 1.f + fabsf((&wo.x)[j]);
            float ang = fmaf(br + bi, __builtin_amdgcn_rcpf(wl),
                             fmaf(2.f, (&bo.x)[j], tphi2));
            float sv, cv;
            __sincosf(ang, &sv, &cv);
            (&oR.x)[j] = cv;
            (&oI.x)[j] = sv;
        }
        or4[c] = oR;
        oi4[c] = oI;
    }
}

extern "C" void kernel_launch(void* const* d_in, const int* in_sizes, int n_in,
                              void* d_out, int out_size, void* d_ws, size_t ws_size,
                              hipStream_t stream) {
    const float* x_real   = (const float*)d_in[0];
    const float* x_imag   = (const float*)d_in[1];
    const float* t_arr    = (const float*)d_in[2];
    const float* w_query  = (const float*)d_in[3];
    const float* b_query  = (const float*)d_in[4];
    const float* w_osc    = (const float*)d_in[5];
    const float* b_osc    = (const float*)d_in[6];
    const float* mem_r    = (const float*)d_in[7];
    const float* mem_i    = (const float*)d_in[8];

    const int B = in_sizes[2];   // t is [B]
    const int D = in_sizes[3];   // w_query is [D]
    const int d4 = D >> 2;
    const int n4 = B * d4;

    float* out_r = (float*)d_out;
    float* out_i = out_r + (size_t)B * D;
    float* alpha_ws = (float*)d_ws;   // B floats

    const float inv_scale = 1.0f / sqrtf((float)D);

    if (d4 == 512 && (B & 15) == 0) {
        // Fast path (bench shape B=8192, D=2048).
        alpha_kernel_fast<<<B >> 4, 256, 0, stream>>>(
            x_real, x_imag, w_query, b_query, alpha_ws, inv_scale);

        int grid2 = 2048;                          // 8 iters/thread at n4=4.19M
        if (grid2 * 256 > n4) grid2 = (n4 + 255) >> 8;
        evolve_kernel_fast<<<grid2, 256, 0, stream>>>(
            x_real, x_imag, t_arr, w_osc, b_osc, mem_r, mem_i, alpha_ws,
            out_r, out_i, n4);
    } else {
        const int grid1 = (B + 3) >> 2;
        alpha_kernel_gen<<<grid1, 256, 0, stream>>>(
            x_real, x_imag, w_query, b_query, alpha_ws, d4, B, inv_scale);
        evolve_kernel_gen<<<B, 256, 0, stream>>>(
            x_real, x_imag, t_arr, w_osc, b_osc, mem_r, mem_i, alpha_ws,
            out_r, out_i, d4);
    }
}

// Round 6
// 317.885 us; speedup vs baseline: 1.0666x; 1.0666x over previous
//
#include <hip/hip_runtime.h>
#include <math.h>

// LiquidEchoHead fused, single kernel, block-per-row (256 thr), d4==512 path.
//
// Diagnosis (rounds 0-4): all prior variants ran at 115 us (2.3 TB/s) while
// the harness's own fill kernel hits 6.9 TB/s. Per-CU arithmetic: 8625
// cycles/block for ~1800 cycles of issue work -> waves idle with ZERO loads
// outstanding. Two causes:
//   (a) __syncthreads forces s_waitcnt vmcnt(0) -> drains prefetch at the
//       reduce window (compiler-mandated drain before s_barrier).
//   (b) phase-2 loads (mem/wo/bo) issued only AFTER the reduction.
// Fix: issue ALL 17 VMEM loads up front into registers (straight-line code,
// no guards so the compiler cannot sink them); reduce across waves via LDS +
// RAW s_barrier (lgkmcnt-only wait, vmcnt prefetch survives); all threads
// recompute alpha redundantly (no second barrier). Nontemporal on the
// streaming x loads and out stores to keep mem_r/mem_i L3-resident.
// NOTE: nontemporal builtins need clang-native vector types, not
// HIP_vector_type -> f32x4 alias.
//
// Identity: cos(a)cos(b)-sin(a)sin(b)=cos(a+b); cos(a)sin(b)+sin(a)cos(b)=sin(a+b)
// -> phase 2 needs one sincos on (theta_r + theta_i).

#define PHI_F 1.61803398874989f

typedef float f32x4 __attribute__((ext_vector_type(4)));

__global__ __launch_bounds__(256) void liquid_echo_fused(
    const float* __restrict__ x_real, const float* __restrict__ x_imag,
    const float* __restrict__ t_arr,
    const float* __restrict__ w_query, const float* __restrict__ b_query,
    const float* __restrict__ w_osc,   const float* __restrict__ b_osc,
    const float* __restrict__ mem_r,   const float* __restrict__ mem_i,
    float* __restrict__ out_r, float* __restrict__ out_i,
    float inv_scale)
{
    const int tid = (int)threadIdx.x;          // 0..255
    const int row = (int)blockIdx.x;
    const size_t base4 = (size_t)row << 9;     // d4 == 512

    const f32x4* xr4 = (const f32x4*)x_real + base4;
    const f32x4* xi4 = (const f32x4*)x_imag + base4;
    const f32x4* wq4 = (const f32x4*)w_query;
    const f32x4* bq4 = (const f32x4*)b_query;
    const f32x4* mr4 = (const f32x4*)mem_r + base4;
    const f32x4* mi4 = (const f32x4*)mem_i + base4;
    const f32x4* wo4 = (const f32x4*)w_osc;
    const f32x4* bo4 = (const f32x4*)b_osc;
    f32x4* or4 = (f32x4*)out_r + base4;
    f32x4* oi4 = (f32x4*)out_i + base4;

    const int c0 = tid;
    const int c1 = tid + 256;

    // ---- Issue ALL global loads up front (17 VMEM ops, counted waits). ----
    // Phase-1 operands first (waited on first); phase-2 operands stay in
    // flight through the reduction and barrier.
    f32x4 xr0 = __builtin_nontemporal_load(&xr4[c0]);    // read-once streams
    f32x4 xr1 = __builtin_nontemporal_load(&xr4[c1]);
    f32x4 xi0 = __builtin_nontemporal_load(&xi4[c0]);
    f32x4 xi1 = __builtin_nontemporal_load(&xi4[c1]);
    f32x4 wq0 = wq4[c0];                                 // L2-hot broadcasts
    f32x4 wq1 = wq4[c1];
    f32x4 bq0 = bq4[c0];
    f32x4 bq1 = bq4[c1];
    f32x4 mr0 = mr4[c0];                                 // L3-resident
    f32x4 mr1 = mr4[c1];
    f32x4 mi0 = mi4[c0];
    f32x4 mi1 = mi4[c1];
    f32x4 wo0 = wo4[c0];
    f32x4 wo1 = wo4[c1];
    f32x4 bo0 = bo4[c0];
    f32x4 bo1 = bo4[c1];
    const float tv = t_arr[row];                         // wave-uniform

    // ---- Phase 1: per-thread interference partials. ----
    float accR = 0.f, accI = 0.f;
    #pragma unroll
    for (int j = 0; j < 4; ++j) {
        float xrv = xr0[j];
        float xiv = xi0[j];
        float wl  = 1.f + fabsf(wq0[j]);
        float th  = xrv * __builtin_amdgcn_rcpf(wl) + bq0[j];
        float sq, cq;
        __sincosf(th, &sq, &cq);
        accR = fmaf(cq, xrv, fmaf(sq, xiv, accR));
        accI = fmaf(cq, xiv, fmaf(-sq, xrv, accI));
    }
    #pragma unroll
    for (int j = 0; j < 4; ++j) {
        float xrv = xr1[j];
        float xiv = xi1[j];
        float wl  = 1.f + fabsf(wq1[j]);
        float th  = xrv * __builtin_amdgcn_rcpf(wl) + bq1[j];
        float sq, cq;
        __sincosf(th, &sq, &cq);
        accR = fmaf(cq, xrv, fmaf(sq, xiv, accR));
        accI = fmaf(cq, xiv, fmaf(-sq, xrv, accI));
    }

    // ---- Wave reduce (butterfly), then cross-wave via LDS + RAW barrier. ----
    #pragma unroll
    for (int off = 32; off > 0; off >>= 1) {
        accR += __shfl_xor(accR, off);
        accI += __shfl_xor(accI, off);
    }
    __shared__ float2 sRI[4];
    const int wave = tid >> 6;
    if ((tid & 63) == 0) sRI[wave] = make_float2(accR, accI);
    // Wait ONLY the LDS write; global (vmcnt) prefetch stays in flight.
    asm volatile("s_waitcnt lgkmcnt(0)" ::: "memory");
    __builtin_amdgcn_s_barrier();
    float2 q0 = sRI[0], q1 = sRI[1], q2 = sRI[2], q3 = sRI[3];  // broadcasts

    // All threads compute alpha redundantly (no second barrier).
    float ir = (q0.x + q1.x) + (q2.x + q3.x);
    float ii = (q0.y + q1.y) + (q2.y + q3.y);
    float interf = sqrtf(fmaf(ir, ir, ii * ii));
    float z     = fmaf(interf, inv_scale, -2.0f);
    float sig   = 1.f / (1.f + __expf(-z));   // sigmoid(z)
    float alpha = __expf(sig - 1.f);          // exp(-k*(1-sig)), k=1
    float beta  = 1.f - alpha;
    float tphi2 = 2.0f * PHI_F * tv;

    // ---- Phase 2: oscillator evolution (operands already in registers). ----
    f32x4 oR, oI;
    #pragma unroll
    for (int j = 0; j < 4; ++j) {
        float br = fmaf(alpha, xr0[j], beta * mr0[j]);
        float bi = fmaf(alpha, xi0[j], beta * mi0[j]);
        float wl = 1.f + fabsf(wo0[j]);
        float ang = fmaf(br + bi, __builtin_amdgcn_rcpf(wl),
                         fmaf(2.f, bo0[j], tphi2));
        float sv, cv;
        __sincosf(ang, &sv, &cv);
        oR[j] = cv;   // evolved_real = cos(theta_r + theta_i)
        oI[j] = sv;   // evolved_imag = sin(theta_r + theta_i)
    }
    __builtin_nontemporal_store(oR, &or4[c0]);
    __builtin_nontemporal_store(oI, &oi4[c0]);
    #pragma unroll
    for (int j = 0; j < 4; ++j) {
        float br = fmaf(alpha, xr1[j], beta * mr1[j]);
        float bi = fmaf(alpha, xi1[j], beta * mi1[j]);
        float wl = 1.f + fabsf(wo1[j]);
        float ang = fmaf(br + bi, __builtin_amdgcn_rcpf(wl),
                         fmaf(2.f, bo1[j], tphi2));
        float sv, cv;
        __sincosf(ang, &sv, &cv);
        oR[j] = cv;
        oI[j] = sv;
    }
    __builtin_nontemporal_store(oR, &or4[c1]);
    __builtin_nontemporal_store(oI, &oi4[c1]);
}

// ---- Generic fallback (any D multiple of 4): round-0 structure. ----
__global__ __launch_bounds__(256) void liquid_echo_gen(
    const float* __restrict__ x_real, const float* __restrict__ x_imag,
    const float* __restrict__ t_arr,
    const float* __restrict__ w_query, const float* __restrict__ b_query,
    const float* __restrict__ w_osc,   const float* __restrict__ b_osc,
    const float* __restrict__ mem_r,   const float* __restrict__ mem_i,
    float* __restrict__ out_r, float* __restrict__ out_i,
    int D, float inv_scale)
{
    const int row = blockIdx.x;
    const int d4  = D >> 2;
    const size_t base4 = (size_t)row * d4;

    const float4* xr4 = (const float4*)x_real + base4;
    const float4* xi4 = (const float4*)x_imag + base4;
    const float4* wq4 = (const float4*)w_query;
    const float4* bq4 = (const float4*)b_query;

    float accR = 0.f, accI = 0.f;
    for (int c = (int)threadIdx.x; c < d4; c += 256) {
        float4 xr = xr4[c];
        float4 xi = xi4[c];
        float4 wq = wq4[c];
        float4 bq = bq4[c];
        #pragma unroll
        for (int j = 0; j < 4; ++j) {
            float xrv = (&xr.x)[j];
            float xiv = (&xi.x)[j];
            float wl  = 1.f + fabsf((&wq.x)[j]);
            float th  = xrv * __builtin_amdgcn_rcpf(wl) + (&bq.x)[j];
            float sq, cq;
            __sincosf(th, &sq, &cq);
            accR = fmaf(cq, xrv, fmaf(sq, xiv, accR));
            accI = fmaf(cq, xiv, fmaf(-sq, xrv, accI));
        }
    }
    #pragma unroll
    for (int off = 32; off > 0; off >>= 1) {
        accR += __shfl_xor(accR, off);
        accI += __shfl_xor(accI, off);
    }
    __shared__ float sR[4], sI[4];
    __shared__ float sAlpha;
    const int wave = (int)threadIdx.x >> 6;
    if ((threadIdx.x & 63) == 0) { sR[wave] = accR; sI[wave] = accI; }
    __syncthreads();
    if (threadIdx.x == 0) {
        float ir = sR[0] + sR[1] + sR[2] + sR[3];
        float ii = sI[0] + sI[1] + sI[2] + sI[3];
        float interf = sqrtf(fmaf(ir, ir, ii * ii));
        float z = fmaf(interf, inv_scale, -2.0f);
        float sig = 1.f / (1.f + __expf(-z));
        sAlpha = __expf(sig - 1.f);
    }
    __syncthreads();

    const float alpha = sAlpha;
    const float beta  = 1.f - alpha;
    const float tphi2 = 2.0f * PHI_F * t_arr[row];

    const float4* wo4 = (const float4*)w_osc;
    const float4* bo4 = (const float4*)b_osc;
    const float4* mr4 = (const float4*)mem_r + base4;
    const float4* mi4 = (const float4*)mem_i + base4;
    float4* or4 = (float4*)out_r + base4;
    float4* oi4 = (float4*)out_i + base4;

    for (int c = (int)threadIdx.x; c < d4; c += 256) {
        float4 xr = xr4[c];
        float4 xi = xi4[c];
        float4 wo = wo4[c];
        float4 bo = bo4[c];
        float4 mr = mr4[c];
        float4 mi = mi4[c];
        float4 oR, oI;
        #pragma unroll
        for (int j = 0; j < 4; ++j) {
            float br = fmaf(alpha, (&xr.x)[j], beta * (&mr.x)[j]);
            float bi = fmaf(alpha, (&xi.x)[j], beta * (&mi.x)[j]);
            float wl = 1.f + fabsf((&wo.x)[j]);
            float ang = fmaf(br + bi, __builtin_amdgcn_rcpf(wl),
                             fmaf(2.f, (&bo.x)[j], tphi2));
            float sv, cv;
            __sincosf(ang, &sv, &cv);
            (&oR.x)[j] = cv;
            (&oI.x)[j] = sv;
        }
        or4[c] = oR;
        oi4[c] = oI;
    }
}

extern "C" void kernel_launch(void* const* d_in, const int* in_sizes, int n_in,
                              void* d_out, int out_size, void* d_ws, size_t ws_size,
                              hipStream_t stream) {
    const float* x_real   = (const float*)d_in[0];
    const float* x_imag   = (const float*)d_in[1];
    const float* t_arr    = (const float*)d_in[2];
    const float* w_query  = (const float*)d_in[3];
    const float* b_query  = (const float*)d_in[4];
    const float* w_osc    = (const float*)d_in[5];
    const float* b_osc    = (const float*)d_in[6];
    const float* mem_r    = (const float*)d_in[7];
    const float* mem_i    = (const float*)d_in[8];

    const int B = in_sizes[2];   // t is [B]
    const int D = in_sizes[3];   // w_query is [D]

    float* out_r = (float*)d_out;
    float* out_i = out_r + (size_t)B * D;

    const float inv_scale = 1.0f / sqrtf((float)D);

    if ((D >> 2) == 512) {
        liquid_echo_fused<<<B, 256, 0, stream>>>(
            x_real, x_imag, t_arr, w_query, b_query, w_osc, b_osc,
            mem_r, mem_i, out_r, out_i, inv_scale);
    } else {
        liquid_echo_gen<<<B, 256, 0, stream>>>(
            x_real, x_imag, t_arr, w_query, b_query, w_osc, b_osc,
            mem_r, mem_i, out_r, out_i, D, inv_scale);
    }
}